// Round 1
// baseline (281.253 us; speedup 1.0000x reference)
//
#include <hip/hip_runtime.h>

#define Bb 256
#define Nn 240
#define Ee 4338
#define Ff 28
#define Uu 100
#define Kk 128            // U + F
#define Mrows (Bb * Nn)   // 61440
#define ET (Ee + Nn)      // edges incl self-loops
#define AS 136            // LDS A-panel row stride in u16 (272B -> <=2-way bank alias)

typedef __attribute__((ext_vector_type(8))) short bf16x8;
typedef __attribute__((ext_vector_type(4))) float f32x4;
typedef unsigned short u16;

__device__ __forceinline__ float bf2f(u16 u) {
  union { unsigned int i; float f; } v; v.i = ((unsigned int)u) << 16; return v.f;
}
__device__ __forceinline__ u16 f2bf(float f) {
  union { float ff; unsigned int i; } v; v.ff = f;
  unsigned int x = v.i;
  return (u16)((x + 0x7fffu + ((x >> 16) & 1u)) >> 16);
}
__device__ __forceinline__ void split4(const float4 v, ushort4& h, ushort4& l) {
  u16 h0 = f2bf(v.x), h1 = f2bf(v.y), h2 = f2bf(v.z), h3 = f2bf(v.w);
  h.x = h0; h.y = h1; h.z = h2; h.w = h3;
  l.x = f2bf(v.x - bf2f(h0)); l.y = f2bf(v.y - bf2f(h1));
  l.z = f2bf(v.z - bf2f(h2)); l.w = f2bf(v.w - bf2f(h3));
}

// ---------------------------------------------------------------------------
// k_prep: fp32 weights -> padded/transposed bf16 hi/lo (unchanged).
// ---------------------------------------------------------------------------
__global__ __launch_bounds__(256) void k_prep(
    const float* __restrict__ Wg, const float* __restrict__ Wru, const float* __restrict__ Wc,
    u16* __restrict__ wgh, u16* __restrict__ wgl,
    u16* __restrict__ wruh, u16* __restrict__ wrul,
    u16* __restrict__ wch, u16* __restrict__ wcl) {
  int gt = blockIdx.x * 256 + threadIdx.x, GS = gridDim.x * 256;
  for (int i = gt; i < 128 * Kk; i += GS) {
    int c = i >> 7, k = i & 127;
    float v = (c < Uu) ? Wg[c * Kk + k] : 0.f;
    u16 h = f2bf(v); wgh[i] = h; wgl[i] = f2bf(v - bf2f(h));
  }
  for (int i = gt; i < 256 * Kk; i += GS) {
    int n = i >> 7, kp = i & 127;
    int k = (kp < Uu) ? (kp + Ff) : (kp - Uu);
    float v = (n < 2 * Uu) ? Wru[k * (2 * Uu) + n] : 0.f;
    u16 h = f2bf(v); wruh[i] = h; wrul[i] = f2bf(v - bf2f(h));
  }
  for (int i = gt; i < 128 * Kk; i += GS) {
    int n = i >> 7, kp = i & 127;
    int k = (kp < Uu) ? (kp + Ff) : (kp - Uu);
    float v = (n < Uu) ? Wc[k * Uu + n] : 0.f;
    u16 h = f2bf(v); wch[i] = h; wcl[i] = f2bf(v - bf2f(h));
  }
}

// ---------------------------------------------------------------------------
// k_csr: dst-grouped CSR (+ self-loop per node), single block.
// r10: thread-0 serial 240-iter prefix scan -> Hillis-Steele LDS scan.
// ---------------------------------------------------------------------------
__global__ __launch_bounds__(256) void k_csr(
    const int* __restrict__ esrc, const int* __restrict__ edst,
    int* __restrict__ coff, int* __restrict__ cslot) {
  __shared__ int cnt[256];
  __shared__ int scan[256];
  __shared__ int cur[Nn];
  int tid = threadIdx.x;
  cnt[tid] = 0;
  __syncthreads();
  for (int e = tid; e < Ee; e += 256) atomicAdd(&cnt[edst[e]], 1);
  __syncthreads();
  int x = (tid < Nn) ? (cnt[tid] + 1) : 0;   // +1 = self-loop slot
  int incl = x;
  scan[tid] = incl;
  __syncthreads();
#pragma unroll
  for (int d = 1; d < 256; d <<= 1) {
    int t = (tid >= d) ? scan[tid - d] : 0;
    __syncthreads();
    incl += t;
    scan[tid] = incl;
    __syncthreads();
  }
  int excl = incl - x;
  if (tid < Nn) { coff[tid] = excl; cur[tid] = excl; }
  if (tid == 0) coff[Nn] = scan[Nn - 1];
  __syncthreads();
  for (int e = tid; e < Ee; e += 256) {
    int d = edst[e];
    cslot[atomicAdd(&cur[d], 1)] = esrc[e];
  }
  for (int n = tid; n < Nn; n += 256) cslot[atomicAdd(&cur[n], 1)] = n;
}

// ---------------------------------------------------------------------------
// k_gemm1: 32 rows/block, 512 threads / 8 waves, ONE tile per wave (1 pass).
// r10: was 256 thr / 2 sequential passes -> halves per-wave critical path and
// doubles resident waves/CU (latency-bound kernel, all pipes <25% busy).
// ---------------------------------------------------------------------------
__global__ __launch_bounds__(512, 8) void k_gemm1(
    const float* __restrict__ stt, const float* __restrict__ inp,
    const u16* __restrict__ wgh, const u16* __restrict__ wgl,
    const float* __restrict__ att_s, const float* __restrict__ att_d,
    float* __restrict__ h, float* __restrict__ asrc, float* __restrict__ adst) {
  __shared__ u16 ahL[32 * AS];
  __shared__ u16 alL[32 * AS];
  __shared__ float sredA[32], sredD[32];
  int tid = threadIdx.x;
  int m0 = blockIdx.x * 32;
  if (tid < 32) sredA[tid] = 0.f;
  else if (tid < 64) sredD[tid - 32] = 0.f;
  for (int j = tid; j < 32 * 32; j += 512) {
    int r = j >> 5, g = j & 31;
    float4 v = (g < 25) ? *(const float4*)(stt + (size_t)(m0 + r) * Uu + g * 4)
                        : *(const float4*)(inp + (size_t)(m0 + r) * Ff + (g - 25) * 4);
    ushort4 hh, ll;
    split4(v, hh, ll);
    *(ushort4*)(ahL + r * AS + g * 4) = hh;
    *(ushort4*)(alL + r * AS + g * 4) = ll;
  }
  __syncthreads();

  int w = tid >> 6, l = tid & 63, l15 = l & 15, q = l >> 4;
  f32x4 zero = {0.f, 0.f, 0.f, 0.f};

  int T = w;                       // tiles 0..7 cover all 128 output cols
  bf16x8 wh[4], wl[4];
#pragma unroll
  for (int s = 0; s < 4; ++s) {
    const int o = (T * 16 + l15) * Kk + s * 32 + q * 8;
    wh[s] = *(const bf16x8*)(wgh + o);
    wl[s] = *(const bf16x8*)(wgl + o);
  }
  f32x4 acc[2];
  acc[0] = zero; acc[1] = zero;
#pragma unroll
  for (int rt = 0; rt < 2; ++rt) {
#pragma unroll
    for (int s = 0; s < 4; ++s) {
      bf16x8 a = *(const bf16x8*)(ahL + (rt * 16 + l15) * AS + s * 32 + q * 8);
      bf16x8 b = *(const bf16x8*)(alL + (rt * 16 + l15) * AS + s * 32 + q * 8);
      acc[rt] = __builtin_amdgcn_mfma_f32_16x16x32_bf16(a, wh[s], acc[rt], 0, 0, 0);
      acc[rt] = __builtin_amdgcn_mfma_f32_16x16x32_bf16(b, wh[s], acc[rt], 0, 0, 0);
      acc[rt] = __builtin_amdgcn_mfma_f32_16x16x32_bf16(a, wl[s], acc[rt], 0, 0, 0);
    }
  }
  int c = T * 16 + l15;
  float av = (c < Uu) ? att_s[c] : 0.f, dv = (c < Uu) ? att_d[c] : 0.f;
#pragma unroll
  for (int rt = 0; rt < 2; ++rt) {
#pragma unroll
    for (int i = 0; i < 4; ++i) {
      float v = acc[rt][i];
      int row = rt * 16 + q * 4 + i;
      if (c < Uu) h[(size_t)(m0 + row) * Uu + c] = v;
      float va = v * av, vd = v * dv;
#pragma unroll
      for (int msk = 1; msk < 16; msk <<= 1) {
        va += __shfl_xor(va, msk, 64);
        vd += __shfl_xor(vd, msk, 64);
      }
      if (l15 == 0) {
        atomicAdd(&sredA[row], va);
        atomicAdd(&sredD[row], vd);
      }
    }
  }
  __syncthreads();
  if (tid < 32) {
    asrc[m0 + tid] = sredA[tid];
    adst[m0 + tid] = sredD[tid];
  }
}

// ---------------------------------------------------------------------------
// k_attn: one WAVE per (sample, dst). Unchanged (passing).
// ---------------------------------------------------------------------------
__global__ __launch_bounds__(256) void k_attn(
    const int* __restrict__ coff, const int* __restrict__ cslot,
    const float* __restrict__ asrc, const float* __restrict__ adst,
    const float* __restrict__ h, const float* __restrict__ gbias, const float* __restrict__ b1,
    float* __restrict__ gsf) {
  int b = blockIdx.x;
  int w = threadIdx.x >> 6, lane = threadIdx.x & 63;
  int n = blockIdx.y * 4 + w;
  int o0 = coff[n], deg = coff[n + 1] - o0;
  float ad = adst[b * Nn + n];
  const float* hb = h + (size_t)b * Nn * Uu;
  int half = lane >> 5, ll = lane & 31;
  bool act = (ll < 25);

  float ax = 0.f, ay = 0.f, az = 0.f, aw = 0.f;
  float den = 0.f;
  for (int c0 = 0; c0 < deg; c0 += 64) {
    int e = c0 + lane;
    float we = 0.f; int s = 0;
    if (e < deg) {
      s = cslot[o0 + e];
      float sc = asrc[b * Nn + s] + ad;
      sc = (sc > 0.f) ? sc : 0.2f * sc;
      we = __expf(sc);
    }
    float d = we;
#pragma unroll
    for (int msk = 1; msk < 64; msk <<= 1) d += __shfl_xor(d, msk, 64);
    den += d;

    int cn = (deg - c0 < 64) ? (deg - c0) : 64;
    for (int e2 = 0; e2 < cn; e2 += 2) {
      int eh = e2 + half;
      float w2 = __shfl(we, eh, 64);
      int s2 = __shfl(s, eh, 64);
      if (act && eh < cn) {
        const float4 hv = *(const float4*)(hb + (size_t)s2 * Uu + ll * 4);
        ax += w2 * hv.x; ay += w2 * hv.y; az += w2 * hv.z; aw += w2 * hv.w;
      }
    }
  }
  ax += __shfl_xor(ax, 32, 64);
  ay += __shfl_xor(ay, 32, 64);
  az += __shfl_xor(az, 32, 64);
  aw += __shfl_xor(aw, 32, 64);
  if (lane < 25) {
    float inv = 1.f / den;
    int u0 = lane * 4;
    float4 o;
    o.x = ax * inv + gbias[u0 + 0] + b1[u0 + 0];
    o.y = ay * inv + gbias[u0 + 1] + b1[u0 + 1];
    o.z = az * inv + gbias[u0 + 2] + b1[u0 + 2];
    o.w = aw * inv + gbias[u0 + 3] + b1[u0 + 3];
    *(float4*)(gsf + ((size_t)b * Nn + n) * Uu + u0) = o;
  }
}

// ---------------------------------------------------------------------------
// k_gru (fused ru + c), 32 rows/block, 512 threads / 8 waves.
// r10: phase1 = 2 passes over 16 ru tiles (was 4), phase2 = 1 pass over 8 c
// tiles (was 2). Pass-0 columns == phase-2 columns (sv/pr alignment):
// cw = w*16 + l15. Doubles resident waves (32/CU at 4 blocks), halves the
// per-wave serial weight-load->MFMA chain.
// ---------------------------------------------------------------------------
__global__ __launch_bounds__(512, 8) void k_gru(
    const float* __restrict__ gsf, const float* __restrict__ inp,
    const u16* __restrict__ wruh, const u16* __restrict__ wrul,
    const float* __restrict__ bru,
    const u16* __restrict__ wch, const u16* __restrict__ wcl,
    const float* __restrict__ bc,
    float* __restrict__ out) {
  __shared__ u16 ahL[32 * AS];
  __shared__ u16 alL[32 * AS];
  __shared__ u16 ugQ[32 * Uu];     // u-gate, 16-bit fixed point
  int tid = threadIdx.x;
  int m0 = blockIdx.x * 32;
  for (int j = tid; j < 32 * 32; j += 512) {
    int r = j >> 5, g = j & 31;
    float4 v = (g < 25) ? *(const float4*)(gsf + (size_t)(m0 + r) * Uu + g * 4)
                        : *(const float4*)(inp + (size_t)(m0 + r) * Ff + (g - 25) * 4);
    ushort4 hh, ll;
    split4(v, hh, ll);
    *(ushort4*)(ahL + r * AS + g * 4) = hh;
    *(ushort4*)(alL + r * AS + g * 4) = ll;
  }

  int w = tid >> 6, l = tid & 63, l15 = l & 15, q = l >> 4;
  int cw = w * 16 + l15;           // pass-0 AND phase-2 column of this wave

  // st preload (independent of LDS; overlaps staging)
  float sv[2][4];
#pragma unroll
  for (int rt = 0; rt < 2; ++rt) {
#pragma unroll
    for (int i = 0; i < 4; ++i) {
      int row = rt * 16 + q * 4 + i;
      sv[rt][i] = (cw < Uu) ? gsf[(size_t)(m0 + row) * Uu + cw] : 0.f;
    }
  }
  __syncthreads();

  f32x4 zero = {0.f, 0.f, 0.f, 0.f};
  float pr[2][4];                  // r*st for this wave's column

  // ---- phase 1: ru, 2 passes of 1 tile (tiles w and w+8) ----
#pragma unroll
  for (int pass = 0; pass < 2; ++pass) {
    int T = pass * 8 + w;
    bf16x8 wh[4], wl[4];
#pragma unroll
    for (int s = 0; s < 4; ++s) {
      const int o = (T * 16 + l15) * Kk + s * 32 + q * 8;
      wh[s] = *(const bf16x8*)(wruh + o);
      wl[s] = *(const bf16x8*)(wrul + o);
    }
    f32x4 acc[2];
    acc[0] = zero; acc[1] = zero;
#pragma unroll
    for (int rt = 0; rt < 2; ++rt) {
#pragma unroll
      for (int s = 0; s < 4; ++s) {
        bf16x8 a = *(const bf16x8*)(ahL + (rt * 16 + l15) * AS + s * 32 + q * 8);
        bf16x8 b = *(const bf16x8*)(alL + (rt * 16 + l15) * AS + s * 32 + q * 8);
        acc[rt] = __builtin_amdgcn_mfma_f32_16x16x32_bf16(a, wh[s], acc[rt], 0, 0, 0);
        acc[rt] = __builtin_amdgcn_mfma_f32_16x16x32_bf16(b, wh[s], acc[rt], 0, 0, 0);
        acc[rt] = __builtin_amdgcn_mfma_f32_16x16x32_bf16(a, wl[s], acc[rt], 0, 0, 0);
      }
    }
    int c = T * 16 + l15;
    float bv = (c < 2 * Uu) ? bru[c] : 0.f;
#pragma unroll
    for (int rt = 0; rt < 2; ++rt) {
#pragma unroll
      for (int i = 0; i < 4; ++i) {
        int row = rt * 16 + q * 4 + i;
        float y = acc[rt][i] + bv;
        float g = 1.f / (1.f + __expf(-y));
        if (pass == 0 && c < Uu) pr[rt][i] = g * sv[rt][i];
        if (c >= Uu && c < 2 * Uu) {
          ugQ[row * Uu + (c - Uu)] = (u16)(g * 65535.f + 0.5f);
        }
      }
    }
  }

  __syncthreads();   // all phase-1 LDS reads + ugQ writes complete
#pragma unroll
  for (int rt = 0; rt < 2; ++rt) {
#pragma unroll
    for (int i = 0; i < 4; ++i) {
      int row = rt * 16 + q * 4 + i;
      if (cw < Uu) {
        float p = pr[rt][i];
        u16 hh = f2bf(p);
        ahL[row * AS + cw] = hh;
        alL[row * AS + cw] = f2bf(p - bf2f(hh));
      }
    }
  }
  __syncthreads();   // cat2 = [r*st | xi] (split) ready in LDS

  // ---- phase 2: c GEMM + blend, 1 pass of 1 tile (tile w) ----
  {
    int T = w;
    bf16x8 wh[4], wl[4];
#pragma unroll
    for (int s = 0; s < 4; ++s) {
      const int o = (T * 16 + l15) * Kk + s * 32 + q * 8;
      wh[s] = *(const bf16x8*)(wch + o);
      wl[s] = *(const bf16x8*)(wcl + o);
    }
    f32x4 acc[2];
    acc[0] = zero; acc[1] = zero;
#pragma unroll
    for (int rt = 0; rt < 2; ++rt) {
#pragma unroll
      for (int s = 0; s < 4; ++s) {
        bf16x8 a = *(const bf16x8*)(ahL + (rt * 16 + l15) * AS + s * 32 + q * 8);
        bf16x8 b = *(const bf16x8*)(alL + (rt * 16 + l15) * AS + s * 32 + q * 8);
        acc[rt] = __builtin_amdgcn_mfma_f32_16x16x32_bf16(a, wh[s], acc[rt], 0, 0, 0);
        acc[rt] = __builtin_amdgcn_mfma_f32_16x16x32_bf16(b, wh[s], acc[rt], 0, 0, 0);
        acc[rt] = __builtin_amdgcn_mfma_f32_16x16x32_bf16(a, wl[s], acc[rt], 0, 0, 0);
      }
    }
    int c = cw;
    float bv = (c < Uu) ? bc[c] : 0.f;
#pragma unroll
    for (int rt = 0; rt < 2; ++rt) {
#pragma unroll
      for (int i = 0; i < 4; ++i) {
        int row = rt * 16 + q * 4 + i;
        if (c < Uu) {
          float y = acc[rt][i] + bv;
          float cv = 1.f - 2.f / (__expf(2.f * y) + 1.f);
          float u = (float)ugQ[row * Uu + c] * (1.f / 65535.f);
          out[(size_t)(m0 + row) * Uu + c] = u * sv[rt][i] + (1.f - u) * cv;
        }
      }
    }
  }
}

// ---------------------------------------------------------------------------
extern "C" void kernel_launch(void* const* d_in, const int* in_sizes, int n_in,
                              void* d_out, int out_size, void* d_ws, size_t ws_size,
                              hipStream_t stream) {
  const float* inp   = (const float*)d_in[0];
  const float* stt   = (const float*)d_in[1];
  const int*   esrc  = (const int*)d_in[2];
  const int*   edst  = (const int*)d_in[3];
  const float* Wg    = (const float*)d_in[4];
  const float* att_s = (const float*)d_in[5];
  const float* att_d = (const float*)d_in[6];
  const float* gbias = (const float*)d_in[7];
  const float* b1    = (const float*)d_in[8];
  const float* Wru   = (const float*)d_in[9];
  const float* bru   = (const float*)d_in[10];
  const float* Wc    = (const float*)d_in[11];
  const float* bc    = (const float*)d_in[12];
  float* out = (float*)d_out;

  char* base = (char*)d_ws;
  size_t o = 0;
  auto alloc = [&](size_t bytes) -> void* {
    void* p = base + o;
    o = (o + bytes + 255) & ~(size_t)255;
    return p;
  };
  u16* wgh  = (u16*)alloc(128 * Kk * sizeof(u16));
  u16* wgl  = (u16*)alloc(128 * Kk * sizeof(u16));
  u16* wruh = (u16*)alloc(256 * Kk * sizeof(u16));
  u16* wrul = (u16*)alloc(256 * Kk * sizeof(u16));
  u16* wch  = (u16*)alloc(128 * Kk * sizeof(u16));
  u16* wcl  = (u16*)alloc(128 * Kk * sizeof(u16));
  int* coff  = (int*)alloc((Nn + 1) * sizeof(int));
  int* cslot = (int*)alloc(ET * sizeof(int));
  float* h    = (float*)alloc((size_t)Mrows * Uu * sizeof(float));
  float* asrc = (float*)alloc((size_t)Mrows * sizeof(float));
  float* adst = (float*)alloc((size_t)Mrows * sizeof(float));
  float* gsf  = (float*)alloc((size_t)Mrows * Uu * sizeof(float));
  // total ~47.6 MB — proven footprint

  k_prep<<<32, 256, 0, stream>>>(Wg, Wru, Wc, wgh, wgl, wruh, wrul, wch, wcl);
  k_csr<<<1, 256, 0, stream>>>(esrc, edst, coff, cslot);
  k_gemm1<<<Mrows / 32, 512, 0, stream>>>(stt, inp, wgh, wgl, att_s, att_d, h, asrc, adst);
  k_attn<<<dim3(Bb, 60), 256, 0, stream>>>(coff, cslot, asrc, adst, h, gbias, b1, gsf);
  k_gru<<<Mrows / 32, 512, 0, stream>>>(gsf, inp, wruh, wrul, bru, wch, wcl, bc, out);
}

// Round 2
// 236.957 us; speedup vs baseline: 1.1869x; 1.1869x over previous
//
#include <hip/hip_runtime.h>

#define Bb 256
#define Nn 240
#define Ee 4338
#define Ff 28
#define Uu 100
#define Kk 128            // U + F
#define Mrows (Bb * Nn)   // 61440
#define ET (Ee + Nn)      // edges incl self-loops
#define AS 136            // LDS A-panel row stride in u16 (272B -> <=2-way bank alias)

typedef __attribute__((ext_vector_type(8))) short bf16x8;
typedef __attribute__((ext_vector_type(4))) float f32x4;
typedef unsigned short u16;

__device__ __forceinline__ float bf2f(u16 u) {
  union { unsigned int i; float f; } v; v.i = ((unsigned int)u) << 16; return v.f;
}
__device__ __forceinline__ u16 f2bf(float f) {
  union { float ff; unsigned int i; } v; v.ff = f;
  unsigned int x = v.i;
  return (u16)((x + 0x7fffu + ((x >> 16) & 1u)) >> 16);
}
__device__ __forceinline__ void split4(const float4 v, ushort4& h, ushort4& l) {
  u16 h0 = f2bf(v.x), h1 = f2bf(v.y), h2 = f2bf(v.z), h3 = f2bf(v.w);
  h.x = h0; h.y = h1; h.z = h2; h.w = h3;
  l.x = f2bf(v.x - bf2f(h0)); l.y = f2bf(v.y - bf2f(h1));
  l.z = f2bf(v.z - bf2f(h2)); l.w = f2bf(v.w - bf2f(h3));
}

// ---------------------------------------------------------------------------
// k_prep: fp32 weights -> padded/transposed bf16 hi/lo (unchanged).
// ---------------------------------------------------------------------------
__global__ __launch_bounds__(256) void k_prep(
    const float* __restrict__ Wg, const float* __restrict__ Wru, const float* __restrict__ Wc,
    u16* __restrict__ wgh, u16* __restrict__ wgl,
    u16* __restrict__ wruh, u16* __restrict__ wrul,
    u16* __restrict__ wch, u16* __restrict__ wcl) {
  int gt = blockIdx.x * 256 + threadIdx.x, GS = gridDim.x * 256;
  for (int i = gt; i < 128 * Kk; i += GS) {
    int c = i >> 7, k = i & 127;
    float v = (c < Uu) ? Wg[c * Kk + k] : 0.f;
    u16 h = f2bf(v); wgh[i] = h; wgl[i] = f2bf(v - bf2f(h));
  }
  for (int i = gt; i < 256 * Kk; i += GS) {
    int n = i >> 7, kp = i & 127;
    int k = (kp < Uu) ? (kp + Ff) : (kp - Uu);
    float v = (n < 2 * Uu) ? Wru[k * (2 * Uu) + n] : 0.f;
    u16 h = f2bf(v); wruh[i] = h; wrul[i] = f2bf(v - bf2f(h));
  }
  for (int i = gt; i < 128 * Kk; i += GS) {
    int n = i >> 7, kp = i & 127;
    int k = (kp < Uu) ? (kp + Ff) : (kp - Uu);
    float v = (n < Uu) ? Wc[k * Uu + n] : 0.f;
    u16 h = f2bf(v); wch[i] = h; wcl[i] = f2bf(v - bf2f(h));
  }
}

// ---------------------------------------------------------------------------
// k_csr: dst-grouped CSR (+ self-loop per node), single block.
// Hillis-Steele LDS scan (r10).
// ---------------------------------------------------------------------------
__global__ __launch_bounds__(256) void k_csr(
    const int* __restrict__ esrc, const int* __restrict__ edst,
    int* __restrict__ coff, int* __restrict__ cslot) {
  __shared__ int cnt[256];
  __shared__ int scan[256];
  __shared__ int cur[Nn];
  int tid = threadIdx.x;
  cnt[tid] = 0;
  __syncthreads();
  for (int e = tid; e < Ee; e += 256) atomicAdd(&cnt[edst[e]], 1);
  __syncthreads();
  int x = (tid < Nn) ? (cnt[tid] + 1) : 0;   // +1 = self-loop slot
  int incl = x;
  scan[tid] = incl;
  __syncthreads();
#pragma unroll
  for (int d = 1; d < 256; d <<= 1) {
    int t = (tid >= d) ? scan[tid - d] : 0;
    __syncthreads();
    incl += t;
    scan[tid] = incl;
    __syncthreads();
  }
  int excl = incl - x;
  if (tid < Nn) { coff[tid] = excl; cur[tid] = excl; }
  if (tid == 0) coff[Nn] = scan[Nn - 1];
  __syncthreads();
  for (int e = tid; e < Ee; e += 256) {
    int d = edst[e];
    cslot[atomicAdd(&cur[d], 1)] = esrc[e];
  }
  for (int n = tid; n < Nn; n += 256) cslot[atomicAdd(&cur[n], 1)] = n;
}

// ---------------------------------------------------------------------------
// k_gemm1: 32 rows/block, 512 threads / 8 waves, ONE tile per wave (1 pass).
// r11: launch_bounds (512,8)->(512,4). The 8-waves/EU cap forced VGPR=32 and
// spilled everything to scratch (FETCH+WRITE blew up 8.5x). 128-VGPR cap lets
// the allocator land at ~64 -> 4 blocks/CU thread-limited, no spill.
// ---------------------------------------------------------------------------
__global__ __launch_bounds__(512, 4) void k_gemm1(
    const float* __restrict__ stt, const float* __restrict__ inp,
    const u16* __restrict__ wgh, const u16* __restrict__ wgl,
    const float* __restrict__ att_s, const float* __restrict__ att_d,
    float* __restrict__ h, float* __restrict__ asrc, float* __restrict__ adst) {
  __shared__ u16 ahL[32 * AS];
  __shared__ u16 alL[32 * AS];
  __shared__ float sredA[32], sredD[32];
  int tid = threadIdx.x;
  int m0 = blockIdx.x * 32;
  if (tid < 32) sredA[tid] = 0.f;
  else if (tid < 64) sredD[tid - 32] = 0.f;
  for (int j = tid; j < 32 * 32; j += 512) {
    int r = j >> 5, g = j & 31;
    float4 v = (g < 25) ? *(const float4*)(stt + (size_t)(m0 + r) * Uu + g * 4)
                        : *(const float4*)(inp + (size_t)(m0 + r) * Ff + (g - 25) * 4);
    ushort4 hh, ll;
    split4(v, hh, ll);
    *(ushort4*)(ahL + r * AS + g * 4) = hh;
    *(ushort4*)(alL + r * AS + g * 4) = ll;
  }
  __syncthreads();

  int w = tid >> 6, l = tid & 63, l15 = l & 15, q = l >> 4;
  f32x4 zero = {0.f, 0.f, 0.f, 0.f};

  int T = w;                       // tiles 0..7 cover all 128 output cols
  bf16x8 wh[4], wl[4];
#pragma unroll
  for (int s = 0; s < 4; ++s) {
    const int o = (T * 16 + l15) * Kk + s * 32 + q * 8;
    wh[s] = *(const bf16x8*)(wgh + o);
    wl[s] = *(const bf16x8*)(wgl + o);
  }
  f32x4 acc[2];
  acc[0] = zero; acc[1] = zero;
#pragma unroll
  for (int rt = 0; rt < 2; ++rt) {
#pragma unroll
    for (int s = 0; s < 4; ++s) {
      bf16x8 a = *(const bf16x8*)(ahL + (rt * 16 + l15) * AS + s * 32 + q * 8);
      bf16x8 b = *(const bf16x8*)(alL + (rt * 16 + l15) * AS + s * 32 + q * 8);
      acc[rt] = __builtin_amdgcn_mfma_f32_16x16x32_bf16(a, wh[s], acc[rt], 0, 0, 0);
      acc[rt] = __builtin_amdgcn_mfma_f32_16x16x32_bf16(b, wh[s], acc[rt], 0, 0, 0);
      acc[rt] = __builtin_amdgcn_mfma_f32_16x16x32_bf16(a, wl[s], acc[rt], 0, 0, 0);
    }
  }
  int c = T * 16 + l15;
  float av = (c < Uu) ? att_s[c] : 0.f, dv = (c < Uu) ? att_d[c] : 0.f;
#pragma unroll
  for (int rt = 0; rt < 2; ++rt) {
#pragma unroll
    for (int i = 0; i < 4; ++i) {
      float v = acc[rt][i];
      int row = rt * 16 + q * 4 + i;
      if (c < Uu) h[(size_t)(m0 + row) * Uu + c] = v;
      float va = v * av, vd = v * dv;
#pragma unroll
      for (int msk = 1; msk < 16; msk <<= 1) {
        va += __shfl_xor(va, msk, 64);
        vd += __shfl_xor(vd, msk, 64);
      }
      if (l15 == 0) {
        atomicAdd(&sredA[row], va);
        atomicAdd(&sredD[row], vd);
      }
    }
  }
  __syncthreads();
  if (tid < 32) {
    asrc[m0 + tid] = sredA[tid];
    adst[m0 + tid] = sredD[tid];
  }
}

// ---------------------------------------------------------------------------
// k_attn: one WAVE per (sample, dst). Unchanged (passing).
// ---------------------------------------------------------------------------
__global__ __launch_bounds__(256) void k_attn(
    const int* __restrict__ coff, const int* __restrict__ cslot,
    const float* __restrict__ asrc, const float* __restrict__ adst,
    const float* __restrict__ h, const float* __restrict__ gbias, const float* __restrict__ b1,
    float* __restrict__ gsf) {
  int b = blockIdx.x;
  int w = threadIdx.x >> 6, lane = threadIdx.x & 63;
  int n = blockIdx.y * 4 + w;
  int o0 = coff[n], deg = coff[n + 1] - o0;
  float ad = adst[b * Nn + n];
  const float* hb = h + (size_t)b * Nn * Uu;
  int half = lane >> 5, ll = lane & 31;
  bool act = (ll < 25);

  float ax = 0.f, ay = 0.f, az = 0.f, aw = 0.f;
  float den = 0.f;
  for (int c0 = 0; c0 < deg; c0 += 64) {
    int e = c0 + lane;
    float we = 0.f; int s = 0;
    if (e < deg) {
      s = cslot[o0 + e];
      float sc = asrc[b * Nn + s] + ad;
      sc = (sc > 0.f) ? sc : 0.2f * sc;
      we = __expf(sc);
    }
    float d = we;
#pragma unroll
    for (int msk = 1; msk < 64; msk <<= 1) d += __shfl_xor(d, msk, 64);
    den += d;

    int cn = (deg - c0 < 64) ? (deg - c0) : 64;
    for (int e2 = 0; e2 < cn; e2 += 2) {
      int eh = e2 + half;
      float w2 = __shfl(we, eh, 64);
      int s2 = __shfl(s, eh, 64);
      if (act && eh < cn) {
        const float4 hv = *(const float4*)(hb + (size_t)s2 * Uu + ll * 4);
        ax += w2 * hv.x; ay += w2 * hv.y; az += w2 * hv.z; aw += w2 * hv.w;
      }
    }
  }
  ax += __shfl_xor(ax, 32, 64);
  ay += __shfl_xor(ay, 32, 64);
  az += __shfl_xor(az, 32, 64);
  aw += __shfl_xor(aw, 32, 64);
  if (lane < 25) {
    float inv = 1.f / den;
    int u0 = lane * 4;
    float4 o;
    o.x = ax * inv + gbias[u0 + 0] + b1[u0 + 0];
    o.y = ay * inv + gbias[u0 + 1] + b1[u0 + 1];
    o.z = az * inv + gbias[u0 + 2] + b1[u0 + 2];
    o.w = aw * inv + gbias[u0 + 3] + b1[u0 + 3];
    *(float4*)(gsf + ((size_t)b * Nn + n) * Uu + u0) = o;
  }
}

// ---------------------------------------------------------------------------
// k_gru (fused ru + c), 32 rows/block, 512 threads / 8 waves.
// Phase1 = 2 passes (tiles w, w+8), phase2 = 1 pass (tile w); pass-0 cols ==
// phase-2 cols (cw = w*16+l15).
// r11: launch_bounds (512,8)->(512,4) — see k_gemm1 note (spill fix).
// ---------------------------------------------------------------------------
__global__ __launch_bounds__(512, 4) void k_gru(
    const float* __restrict__ gsf, const float* __restrict__ inp,
    const u16* __restrict__ wruh, const u16* __restrict__ wrul,
    const float* __restrict__ bru,
    const u16* __restrict__ wch, const u16* __restrict__ wcl,
    const float* __restrict__ bc,
    float* __restrict__ out) {
  __shared__ u16 ahL[32 * AS];
  __shared__ u16 alL[32 * AS];
  __shared__ u16 ugQ[32 * Uu];     // u-gate, 16-bit fixed point
  int tid = threadIdx.x;
  int m0 = blockIdx.x * 32;
  for (int j = tid; j < 32 * 32; j += 512) {
    int r = j >> 5, g = j & 31;
    float4 v = (g < 25) ? *(const float4*)(gsf + (size_t)(m0 + r) * Uu + g * 4)
                        : *(const float4*)(inp + (size_t)(m0 + r) * Ff + (g - 25) * 4);
    ushort4 hh, ll;
    split4(v, hh, ll);
    *(ushort4*)(ahL + r * AS + g * 4) = hh;
    *(ushort4*)(alL + r * AS + g * 4) = ll;
  }

  int w = tid >> 6, l = tid & 63, l15 = l & 15, q = l >> 4;
  int cw = w * 16 + l15;           // pass-0 AND phase-2 column of this wave

  // st preload (independent of LDS; overlaps staging)
  float sv[2][4];
#pragma unroll
  for (int rt = 0; rt < 2; ++rt) {
#pragma unroll
    for (int i = 0; i < 4; ++i) {
      int row = rt * 16 + q * 4 + i;
      sv[rt][i] = (cw < Uu) ? gsf[(size_t)(m0 + row) * Uu + cw] : 0.f;
    }
  }
  __syncthreads();

  f32x4 zero = {0.f, 0.f, 0.f, 0.f};
  float pr[2][4];                  // r*st for this wave's column

  // ---- phase 1: ru, 2 passes of 1 tile (tiles w and w+8) ----
#pragma unroll
  for (int pass = 0; pass < 2; ++pass) {
    int T = pass * 8 + w;
    bf16x8 wh[4], wl[4];
#pragma unroll
    for (int s = 0; s < 4; ++s) {
      const int o = (T * 16 + l15) * Kk + s * 32 + q * 8;
      wh[s] = *(const bf16x8*)(wruh + o);
      wl[s] = *(const bf16x8*)(wrul + o);
    }
    f32x4 acc[2];
    acc[0] = zero; acc[1] = zero;
#pragma unroll
    for (int rt = 0; rt < 2; ++rt) {
#pragma unroll
      for (int s = 0; s < 4; ++s) {
        bf16x8 a = *(const bf16x8*)(ahL + (rt * 16 + l15) * AS + s * 32 + q * 8);
        bf16x8 b = *(const bf16x8*)(alL + (rt * 16 + l15) * AS + s * 32 + q * 8);
        acc[rt] = __builtin_amdgcn_mfma_f32_16x16x32_bf16(a, wh[s], acc[rt], 0, 0, 0);
        acc[rt] = __builtin_amdgcn_mfma_f32_16x16x32_bf16(b, wh[s], acc[rt], 0, 0, 0);
        acc[rt] = __builtin_amdgcn_mfma_f32_16x16x32_bf16(a, wl[s], acc[rt], 0, 0, 0);
      }
    }
    int c = T * 16 + l15;
    float bv = (c < 2 * Uu) ? bru[c] : 0.f;
#pragma unroll
    for (int rt = 0; rt < 2; ++rt) {
#pragma unroll
      for (int i = 0; i < 4; ++i) {
        int row = rt * 16 + q * 4 + i;
        float y = acc[rt][i] + bv;
        float g = 1.f / (1.f + __expf(-y));
        if (pass == 0 && c < Uu) pr[rt][i] = g * sv[rt][i];
        if (c >= Uu && c < 2 * Uu) {
          ugQ[row * Uu + (c - Uu)] = (u16)(g * 65535.f + 0.5f);
        }
      }
    }
  }

  __syncthreads();   // all phase-1 LDS reads + ugQ writes complete
#pragma unroll
  for (int rt = 0; rt < 2; ++rt) {
#pragma unroll
    for (int i = 0; i < 4; ++i) {
      int row = rt * 16 + q * 4 + i;
      if (cw < Uu) {
        float p = pr[rt][i];
        u16 hh = f2bf(p);
        ahL[row * AS + cw] = hh;
        alL[row * AS + cw] = f2bf(p - bf2f(hh));
      }
    }
  }
  __syncthreads();   // cat2 = [r*st | xi] (split) ready in LDS

  // ---- phase 2: c GEMM + blend, 1 pass of 1 tile (tile w) ----
  {
    int T = w;
    bf16x8 wh[4], wl[4];
#pragma unroll
    for (int s = 0; s < 4; ++s) {
      const int o = (T * 16 + l15) * Kk + s * 32 + q * 8;
      wh[s] = *(const bf16x8*)(wch + o);
      wl[s] = *(const bf16x8*)(wcl + o);
    }
    f32x4 acc[2];
    acc[0] = zero; acc[1] = zero;
#pragma unroll
    for (int rt = 0; rt < 2; ++rt) {
#pragma unroll
      for (int s = 0; s < 4; ++s) {
        bf16x8 a = *(const bf16x8*)(ahL + (rt * 16 + l15) * AS + s * 32 + q * 8);
        bf16x8 b = *(const bf16x8*)(alL + (rt * 16 + l15) * AS + s * 32 + q * 8);
        acc[rt] = __builtin_amdgcn_mfma_f32_16x16x32_bf16(a, wh[s], acc[rt], 0, 0, 0);
        acc[rt] = __builtin_amdgcn_mfma_f32_16x16x32_bf16(b, wh[s], acc[rt], 0, 0, 0);
        acc[rt] = __builtin_amdgcn_mfma_f32_16x16x32_bf16(a, wl[s], acc[rt], 0, 0, 0);
      }
    }
    int c = cw;
    float bv = (c < Uu) ? bc[c] : 0.f;
#pragma unroll
    for (int rt = 0; rt < 2; ++rt) {
#pragma unroll
      for (int i = 0; i < 4; ++i) {
        int row = rt * 16 + q * 4 + i;
        if (c < Uu) {
          float y = acc[rt][i] + bv;
          float cv = 1.f - 2.f / (__expf(2.f * y) + 1.f);
          float u = (float)ugQ[row * Uu + c] * (1.f / 65535.f);
          out[(size_t)(m0 + row) * Uu + c] = u * sv[rt][i] + (1.f - u) * cv;
        }
      }
    }
  }
}

// ---------------------------------------------------------------------------
extern "C" void kernel_launch(void* const* d_in, const int* in_sizes, int n_in,
                              void* d_out, int out_size, void* d_ws, size_t ws_size,
                              hipStream_t stream) {
  const float* inp   = (const float*)d_in[0];
  const float* stt   = (const float*)d_in[1];
  const int*   esrc  = (const int*)d_in[2];
  const int*   edst  = (const int*)d_in[3];
  const float* Wg    = (const float*)d_in[4];
  const float* att_s = (const float*)d_in[5];
  const float* att_d = (const float*)d_in[6];
  const float* gbias = (const float*)d_in[7];
  const float* b1    = (const float*)d_in[8];
  const float* Wru   = (const float*)d_in[9];
  const float* bru   = (const float*)d_in[10];
  const float* Wc    = (const float*)d_in[11];
  const float* bc    = (const float*)d_in[12];
  float* out = (float*)d_out;

  char* base = (char*)d_ws;
  size_t o = 0;
  auto alloc = [&](size_t bytes) -> void* {
    void* p = base + o;
    o = (o + bytes + 255) & ~(size_t)255;
    return p;
  };
  u16* wgh  = (u16*)alloc(128 * Kk * sizeof(u16));
  u16* wgl  = (u16*)alloc(128 * Kk * sizeof(u16));
  u16* wruh = (u16*)alloc(256 * Kk * sizeof(u16));
  u16* wrul = (u16*)alloc(256 * Kk * sizeof(u16));
  u16* wch  = (u16*)alloc(128 * Kk * sizeof(u16));
  u16* wcl  = (u16*)alloc(128 * Kk * sizeof(u16));
  int* coff  = (int*)alloc((Nn + 1) * sizeof(int));
  int* cslot = (int*)alloc(ET * sizeof(int));
  float* h    = (float*)alloc((size_t)Mrows * Uu * sizeof(float));
  float* asrc = (float*)alloc((size_t)Mrows * sizeof(float));
  float* adst = (float*)alloc((size_t)Mrows * sizeof(float));
  float* gsf  = (float*)alloc((size_t)Mrows * Uu * sizeof(float));
  // total ~47.6 MB — proven footprint

  k_prep<<<32, 256, 0, stream>>>(Wg, Wru, Wc, wgh, wgl, wruh, wrul, wch, wcl);
  k_csr<<<1, 256, 0, stream>>>(esrc, edst, coff, cslot);
  k_gemm1<<<Mrows / 32, 512, 0, stream>>>(stt, inp, wgh, wgl, att_s, att_d, h, asrc, adst);
  k_attn<<<dim3(Bb, 60), 256, 0, stream>>>(coff, cslot, asrc, adst, h, gbias, b1, gsf);
  k_gru<<<Mrows / 32, 512, 0, stream>>>(gsf, inp, wruh, wrul, bru, wch, wcl, bc, out);
}

// Round 3
// 230.934 us; speedup vs baseline: 1.2179x; 1.0261x over previous
//
#include <hip/hip_runtime.h>

#define Bb 256
#define Nn 240
#define Ee 4338
#define Ff 28
#define Uu 100
#define Kk 128            // U + F
#define Mrows (Bb * Nn)   // 61440
#define ET (Ee + Nn)      // edges incl self-loops
#define AS 136            // LDS A-panel row stride in u16

typedef __attribute__((ext_vector_type(8))) short bf16x8;
typedef __attribute__((ext_vector_type(4))) float f32x4;
typedef unsigned short u16;

__device__ __forceinline__ float bf2f(u16 u) {
  union { unsigned int i; float f; } v; v.i = ((unsigned int)u) << 16; return v.f;
}
__device__ __forceinline__ u16 f2bf(float f) {
  union { float ff; unsigned int i; } v; v.ff = f;
  unsigned int x = v.i;
  return (u16)((x + 0x7fffu + ((x >> 16) & 1u)) >> 16);
}
__device__ __forceinline__ void split4(const float4 v, ushort4& h, ushort4& l) {
  u16 h0 = f2bf(v.x), h1 = f2bf(v.y), h2 = f2bf(v.z), h3 = f2bf(v.w);
  h.x = h0; h.y = h1; h.z = h2; h.w = h3;
  l.x = f2bf(v.x - bf2f(h0)); l.y = f2bf(v.y - bf2f(h1));
  l.z = f2bf(v.z - bf2f(h2)); l.w = f2bf(v.w - bf2f(h3));
}

// ---------------------------------------------------------------------------
// k_prep: fp32 weights -> padded/transposed bf16 hi/lo (unchanged).
// ---------------------------------------------------------------------------
__global__ __launch_bounds__(256) void k_prep(
    const float* __restrict__ Wg, const float* __restrict__ Wru, const float* __restrict__ Wc,
    u16* __restrict__ wgh, u16* __restrict__ wgl,
    u16* __restrict__ wruh, u16* __restrict__ wrul,
    u16* __restrict__ wch, u16* __restrict__ wcl) {
  int gt = blockIdx.x * 256 + threadIdx.x, GS = gridDim.x * 256;
  for (int i = gt; i < 128 * Kk; i += GS) {
    int c = i >> 7, k = i & 127;
    float v = (c < Uu) ? Wg[c * Kk + k] : 0.f;
    u16 h = f2bf(v); wgh[i] = h; wgl[i] = f2bf(v - bf2f(h));
  }
  for (int i = gt; i < 256 * Kk; i += GS) {
    int n = i >> 7, kp = i & 127;
    int k = (kp < Uu) ? (kp + Ff) : (kp - Uu);
    float v = (n < 2 * Uu) ? Wru[k * (2 * Uu) + n] : 0.f;
    u16 h = f2bf(v); wruh[i] = h; wrul[i] = f2bf(v - bf2f(h));
  }
  for (int i = gt; i < 128 * Kk; i += GS) {
    int n = i >> 7, kp = i & 127;
    int k = (kp < Uu) ? (kp + Ff) : (kp - Uu);
    float v = (n < Uu) ? Wc[k * Uu + n] : 0.f;
    u16 h = f2bf(v); wch[i] = h; wcl[i] = f2bf(v - bf2f(h));
  }
}

// ---------------------------------------------------------------------------
// k_csr: dst-grouped CSR (+ self-loop per node), single block (unchanged).
// ---------------------------------------------------------------------------
__global__ __launch_bounds__(256) void k_csr(
    const int* __restrict__ esrc, const int* __restrict__ edst,
    int* __restrict__ coff, int* __restrict__ cslot) {
  __shared__ int cnt[256];
  __shared__ int scan[256];
  __shared__ int cur[Nn];
  int tid = threadIdx.x;
  cnt[tid] = 0;
  __syncthreads();
  for (int e = tid; e < Ee; e += 256) atomicAdd(&cnt[edst[e]], 1);
  __syncthreads();
  int x = (tid < Nn) ? (cnt[tid] + 1) : 0;   // +1 = self-loop slot
  int incl = x;
  scan[tid] = incl;
  __syncthreads();
#pragma unroll
  for (int d = 1; d < 256; d <<= 1) {
    int t = (tid >= d) ? scan[tid - d] : 0;
    __syncthreads();
    incl += t;
    scan[tid] = incl;
    __syncthreads();
  }
  int excl = incl - x;
  if (tid < Nn) { coff[tid] = excl; cur[tid] = excl; }
  if (tid == 0) coff[Nn] = scan[Nn - 1];
  __syncthreads();
  for (int e = tid; e < Ee; e += 256) {
    int d = edst[e];
    cslot[atomicAdd(&cur[d], 1)] = esrc[e];
  }
  for (int n = tid; n < Nn; n += 256) cslot[atomicAdd(&cur[n], 1)] = n;
}

// ---------------------------------------------------------------------------
// k_fused: ONE BLOCK PER SAMPLE (256 blocks, 512 thr, ~150 KB LDS, 1 blk/CU).
// r12: fuses k_gemm1 + k_attn + k_gru. h lives in LDS (96 KB) — no HBM
// round-trip for h/asrc/adst/gsf; weight frags loaded ONCE into VGPRs (96
// regs held across the row-chunk loop); GRU runs per-32-row chunk right
// after that chunk's attention. Numerics ordering identical to r11.
// ---------------------------------------------------------------------------
__global__ __launch_bounds__(512, 2) void k_fused(
    const float* __restrict__ stt, const float* __restrict__ inp,
    const u16* __restrict__ wgh, const u16* __restrict__ wgl,
    const float* __restrict__ att_s, const float* __restrict__ att_d,
    const int* __restrict__ coff, const int* __restrict__ cslot,
    const float* __restrict__ gbias, const float* __restrict__ b1,
    const u16* __restrict__ wruh, const u16* __restrict__ wrul,
    const float* __restrict__ bru,
    const u16* __restrict__ wch, const u16* __restrict__ wcl,
    const float* __restrict__ bc,
    float* __restrict__ out) {
  __shared__ float hbuf[Nn * Uu];      // 96,000 B : h (fp32), full sample
  __shared__ u16 ahL[32 * AS];         //  8,704 B : A-panel hi
  __shared__ u16 alL[32 * AS];         //  8,704 B : A-panel lo
  __shared__ float gch[32 * Uu];       // 12,800 B : gstate chunk (fp32)
  __shared__ u16 ugQ[32 * Uu];         //  6,400 B : u-gate chunk (u16 fixpt)
  __shared__ float asrcL[Nn];          //    960 B
  __shared__ float adstL[Nn];          //    960 B
  __shared__ int coffL[Nn + 1];        //    964 B
  __shared__ int cslotL[ET];           // 18,312 B  -> total ~153.8 KB

  int tid = threadIdx.x;
  int b = blockIdx.x;
  const size_t sbase = (size_t)b * Nn * Uu;
  const size_t ibase = (size_t)b * Nn * Ff;

  // ---- init: CSR to LDS, zero att accumulators ----
  for (int i = tid; i < Nn + 1; i += 512) coffL[i] = coff[i];
  for (int i = tid; i < ET; i += 512) cslotL[i] = cslot[i];
  for (int i = tid; i < Nn; i += 512) { asrcL[i] = 0.f; adstL[i] = 0.f; }

  int w = tid >> 6, l = tid & 63, l15 = l & 15, q = l >> 4;
  int cw = w * 16 + l15;               // this wave's output column
  int llb = l & 31, half = l >> 5;

  float4 gbv = {0.f, 0.f, 0.f, 0.f};   // gat_bias + bias1, lanes 0..24
  if (l < 25) {
    int u0 = l * 4;
    gbv.x = gbias[u0 + 0] + b1[u0 + 0];
    gbv.y = gbias[u0 + 1] + b1[u0 + 1];
    gbv.z = gbias[u0 + 2] + b1[u0 + 2];
    gbv.w = gbias[u0 + 3] + b1[u0 + 3];
  }

  f32x4 zero = {0.f, 0.f, 0.f, 0.f};

  // ================= phase A: h = x @ Wg^T, att dots =================
  {
    bf16x8 wh[4], wl[4];
#pragma unroll
    for (int s = 0; s < 4; ++s) {
      const int o = cw * Kk + s * 32 + q * 8;
      wh[s] = *(const bf16x8*)(wgh + o);
      wl[s] = *(const bf16x8*)(wgl + o);
    }
    float av = (cw < Uu) ? att_s[cw] : 0.f;
    float dv = (cw < Uu) ? att_d[cw] : 0.f;

    for (int ch0 = 0; ch0 < Nn; ch0 += 32) {
      int rows = Nn - ch0; if (rows > 32) rows = 32;
      int nrt = rows >> 4;
      for (int j = tid; j < rows * 32; j += 512) {
        int r = j >> 5, g = j & 31;
        float4 v = (g < 25)
            ? *(const float4*)(stt + sbase + (size_t)(ch0 + r) * Uu + g * 4)
            : *(const float4*)(inp + ibase + (size_t)(ch0 + r) * Ff + (g - 25) * 4);
        ushort4 hh, lo;
        split4(v, hh, lo);
        *(ushort4*)(ahL + r * AS + g * 4) = hh;
        *(ushort4*)(alL + r * AS + g * 4) = lo;
      }
      __syncthreads();
      f32x4 acc[2]; acc[0] = zero; acc[1] = zero;
#pragma unroll
      for (int rt = 0; rt < 2; ++rt) if (rt < nrt) {
#pragma unroll
        for (int s = 0; s < 4; ++s) {
          bf16x8 a = *(const bf16x8*)(ahL + (rt * 16 + l15) * AS + s * 32 + q * 8);
          bf16x8 bb = *(const bf16x8*)(alL + (rt * 16 + l15) * AS + s * 32 + q * 8);
          acc[rt] = __builtin_amdgcn_mfma_f32_16x16x32_bf16(a, wh[s], acc[rt], 0, 0, 0);
          acc[rt] = __builtin_amdgcn_mfma_f32_16x16x32_bf16(bb, wh[s], acc[rt], 0, 0, 0);
          acc[rt] = __builtin_amdgcn_mfma_f32_16x16x32_bf16(a, wl[s], acc[rt], 0, 0, 0);
        }
      }
#pragma unroll
      for (int rt = 0; rt < 2; ++rt) if (rt < nrt) {
#pragma unroll
        for (int i = 0; i < 4; ++i) {
          float v = acc[rt][i];
          int row = rt * 16 + q * 4 + i;
          if (cw < Uu) hbuf[(ch0 + row) * Uu + cw] = v;
          float va = v * av, vd = v * dv;
#pragma unroll
          for (int msk = 1; msk < 16; msk <<= 1) {
            va += __shfl_xor(va, msk, 64);
            vd += __shfl_xor(vd, msk, 64);
          }
          if (l15 == 0) {
            atomicAdd(&asrcL[ch0 + row], va);
            atomicAdd(&adstL[ch0 + row], vd);
          }
        }
      }
      __syncthreads();
    }
  }

  // ---- preload GRU weight fragments (held in VGPRs across all chunks) ----
  bf16x8 r0h[4], r0l[4], r1h[4], r1l[4], cch[4], ccl[4];
  int cw1 = 128 + cw;                  // ru pass-1 column
#pragma unroll
  for (int s = 0; s < 4; ++s) {
    const int o0 = cw * Kk + s * 32 + q * 8;
    const int o1 = cw1 * Kk + s * 32 + q * 8;
    r0h[s] = *(const bf16x8*)(wruh + o0);
    r0l[s] = *(const bf16x8*)(wrul + o0);
    r1h[s] = *(const bf16x8*)(wruh + o1);
    r1l[s] = *(const bf16x8*)(wrul + o1);
    cch[s] = *(const bf16x8*)(wch + o0);
    ccl[s] = *(const bf16x8*)(wcl + o0);
  }
  float bru0 = bru[cw];
  float bru1 = (cw1 < 2 * Uu) ? bru[cw1] : 0.f;
  float bcv = (cw < Uu) ? bc[cw] : 0.f;

  // ============ phase B+C per 32-row chunk: attention then GRU ============
  for (int ch0 = 0; ch0 < Nn; ch0 += 32) {
    int rows = Nn - ch0; if (rows > 32) rows = 32;
    int nrt = rows >> 4;

    // ---- B: attention for dst nodes [ch0, ch0+rows), one dst per wave ----
    for (int n = ch0 + w; n < ch0 + rows; n += 8) {
      int o0 = coffL[n], deg = coffL[n + 1] - o0;
      float ad = adstL[n];
      float ax = 0.f, ay = 0.f, az = 0.f, aw2 = 0.f, den = 0.f;
      for (int c0 = 0; c0 < deg; c0 += 64) {
        int e = c0 + l;
        float we = 0.f; int s = 0;
        if (e < deg) {
          s = cslotL[o0 + e];
          float sc = asrcL[s] + ad;
          sc = (sc > 0.f) ? sc : 0.2f * sc;
          we = __expf(sc);
        }
        float d = we;
#pragma unroll
        for (int msk = 1; msk < 64; msk <<= 1) d += __shfl_xor(d, msk, 64);
        den += d;
        int cn = deg - c0; if (cn > 64) cn = 64;
        for (int e2 = 0; e2 < cn; e2 += 2) {
          int eh = e2 + half;
          float w2 = __shfl(we, eh, 64);
          int s2 = __shfl(s, eh, 64);
          if ((llb < 25) && eh < cn) {
            const float4 hv = *(const float4*)(hbuf + s2 * Uu + llb * 4);
            ax += w2 * hv.x; ay += w2 * hv.y; az += w2 * hv.z; aw2 += w2 * hv.w;
          }
        }
      }
      ax += __shfl_xor(ax, 32, 64);
      ay += __shfl_xor(ay, 32, 64);
      az += __shfl_xor(az, 32, 64);
      aw2 += __shfl_xor(aw2, 32, 64);
      if (l < 25) {
        float inv = 1.f / den;
        float4 o;
        o.x = ax * inv + gbv.x;
        o.y = ay * inv + gbv.y;
        o.z = az * inv + gbv.z;
        o.w = aw2 * inv + gbv.w;
        *(float4*)(gch + (n - ch0) * Uu + l * 4) = o;
      }
    }
    __syncthreads();   // gch complete; all waves past previous chunk's C

    // ---- C: GRU for rows [ch0, ch0+rows) ----
    for (int j = tid; j < rows * 32; j += 512) {
      int r = j >> 5, g = j & 31;
      float4 v = (g < 25)
          ? *(const float4*)(gch + r * Uu + g * 4)
          : *(const float4*)(inp + ibase + (size_t)(ch0 + r) * Ff + (g - 25) * 4);
      ushort4 hh, lo;
      split4(v, hh, lo);
      *(ushort4*)(ahL + r * AS + g * 4) = hh;
      *(ushort4*)(alL + r * AS + g * 4) = lo;
    }
    float sv[2][4];
#pragma unroll
    for (int rt = 0; rt < 2; ++rt) if (rt < nrt) {
#pragma unroll
      for (int i = 0; i < 4; ++i) {
        int row = rt * 16 + q * 4 + i;
        sv[rt][i] = (cw < Uu) ? gch[row * Uu + cw] : 0.f;
      }
    }
    __syncthreads();   // staging + sv reads of gch done

    float pr[2][4];
    // ru pass 0: tiles 0..7 (cols cw) -> r-gate (c<100) + u-gate (100..127)
    {
      f32x4 acc[2]; acc[0] = zero; acc[1] = zero;
#pragma unroll
      for (int rt = 0; rt < 2; ++rt) if (rt < nrt) {
#pragma unroll
        for (int s = 0; s < 4; ++s) {
          bf16x8 a = *(const bf16x8*)(ahL + (rt * 16 + l15) * AS + s * 32 + q * 8);
          bf16x8 bb = *(const bf16x8*)(alL + (rt * 16 + l15) * AS + s * 32 + q * 8);
          acc[rt] = __builtin_amdgcn_mfma_f32_16x16x32_bf16(a, r0h[s], acc[rt], 0, 0, 0);
          acc[rt] = __builtin_amdgcn_mfma_f32_16x16x32_bf16(bb, r0h[s], acc[rt], 0, 0, 0);
          acc[rt] = __builtin_amdgcn_mfma_f32_16x16x32_bf16(a, r0l[s], acc[rt], 0, 0, 0);
        }
      }
#pragma unroll
      for (int rt = 0; rt < 2; ++rt) if (rt < nrt) {
#pragma unroll
        for (int i = 0; i < 4; ++i) {
          int row = rt * 16 + q * 4 + i;
          float y = acc[rt][i] + bru0;
          float g = 1.f / (1.f + __expf(-y));
          if (cw < Uu) pr[rt][i] = g * sv[rt][i];
          else ugQ[row * Uu + (cw - Uu)] = (u16)(g * 65535.f + 0.5f);
        }
      }
    }
    // ru pass 1: tiles 8..15 (cols cw1 in [128,256)) -> u-gate (128..199)
    {
      f32x4 acc[2]; acc[0] = zero; acc[1] = zero;
#pragma unroll
      for (int rt = 0; rt < 2; ++rt) if (rt < nrt) {
#pragma unroll
        for (int s = 0; s < 4; ++s) {
          bf16x8 a = *(const bf16x8*)(ahL + (rt * 16 + l15) * AS + s * 32 + q * 8);
          bf16x8 bb = *(const bf16x8*)(alL + (rt * 16 + l15) * AS + s * 32 + q * 8);
          acc[rt] = __builtin_amdgcn_mfma_f32_16x16x32_bf16(a, r1h[s], acc[rt], 0, 0, 0);
          acc[rt] = __builtin_amdgcn_mfma_f32_16x16x32_bf16(bb, r1h[s], acc[rt], 0, 0, 0);
          acc[rt] = __builtin_amdgcn_mfma_f32_16x16x32_bf16(a, r1l[s], acc[rt], 0, 0, 0);
        }
      }
#pragma unroll
      for (int rt = 0; rt < 2; ++rt) if (rt < nrt) {
#pragma unroll
        for (int i = 0; i < 4; ++i) {
          int row = rt * 16 + q * 4 + i;
          float y = acc[rt][i] + bru1;
          float g = 1.f / (1.f + __expf(-y));
          if (cw1 < 2 * Uu) ugQ[row * Uu + (cw1 - Uu)] = (u16)(g * 65535.f + 0.5f);
        }
      }
    }
    __syncthreads();   // all ru LDS reads + ugQ writes complete

    // substitute r*st into A-panel cols < 100
#pragma unroll
    for (int rt = 0; rt < 2; ++rt) if (rt < nrt) {
#pragma unroll
      for (int i = 0; i < 4; ++i) {
        int row = rt * 16 + q * 4 + i;
        if (cw < Uu) {
          float p = pr[rt][i];
          u16 hh = f2bf(p);
          ahL[row * AS + cw] = hh;
          alL[row * AS + cw] = f2bf(p - bf2f(hh));
        }
      }
    }
    __syncthreads();   // cat2 = [r*st | xi] ready

    // c GEMM + blend, tile w (cols cw)
    {
      f32x4 acc[2]; acc[0] = zero; acc[1] = zero;
#pragma unroll
      for (int rt = 0; rt < 2; ++rt) if (rt < nrt) {
#pragma unroll
        for (int s = 0; s < 4; ++s) {
          bf16x8 a = *(const bf16x8*)(ahL + (rt * 16 + l15) * AS + s * 32 + q * 8);
          bf16x8 bb = *(const bf16x8*)(alL + (rt * 16 + l15) * AS + s * 32 + q * 8);
          acc[rt] = __builtin_amdgcn_mfma_f32_16x16x32_bf16(a, cch[s], acc[rt], 0, 0, 0);
          acc[rt] = __builtin_amdgcn_mfma_f32_16x16x32_bf16(bb, cch[s], acc[rt], 0, 0, 0);
          acc[rt] = __builtin_amdgcn_mfma_f32_16x16x32_bf16(a, ccl[s], acc[rt], 0, 0, 0);
        }
      }
#pragma unroll
      for (int rt = 0; rt < 2; ++rt) if (rt < nrt) {
#pragma unroll
        for (int i = 0; i < 4; ++i) {
          int row = rt * 16 + q * 4 + i;
          if (cw < Uu) {
            float y = acc[rt][i] + bcv;
            float cv = 1.f - 2.f / (__expf(2.f * y) + 1.f);
            float u = (float)ugQ[row * Uu + cw] * (1.f / 65535.f);
            out[sbase + (size_t)(ch0 + row) * Uu + cw] = u * sv[rt][i] + (1.f - u) * cv;
          }
        }
      }
    }
    // no trailing barrier needed: next chunk's B only writes gch (readers all
    // passed the post-staging sync) and the post-B sync orders ahL reuse.
  }
}

// ---------------------------------------------------------------------------
extern "C" void kernel_launch(void* const* d_in, const int* in_sizes, int n_in,
                              void* d_out, int out_size, void* d_ws, size_t ws_size,
                              hipStream_t stream) {
  const float* inp   = (const float*)d_in[0];
  const float* stt   = (const float*)d_in[1];
  const int*   esrc  = (const int*)d_in[2];
  const int*   edst  = (const int*)d_in[3];
  const float* Wg    = (const float*)d_in[4];
  const float* att_s = (const float*)d_in[5];
  const float* att_d = (const float*)d_in[6];
  const float* gbias = (const float*)d_in[7];
  const float* b1    = (const float*)d_in[8];
  const float* Wru   = (const float*)d_in[9];
  const float* bru   = (const float*)d_in[10];
  const float* Wc    = (const float*)d_in[11];
  const float* bc    = (const float*)d_in[12];
  float* out = (float*)d_out;

  char* base = (char*)d_ws;
  size_t o = 0;
  auto alloc = [&](size_t bytes) -> void* {
    void* p = base + o;
    o = (o + bytes + 255) & ~(size_t)255;
    return p;
  };
  u16* wgh  = (u16*)alloc(128 * Kk * sizeof(u16));
  u16* wgl  = (u16*)alloc(128 * Kk * sizeof(u16));
  u16* wruh = (u16*)alloc(256 * Kk * sizeof(u16));
  u16* wrul = (u16*)alloc(256 * Kk * sizeof(u16));
  u16* wch  = (u16*)alloc(128 * Kk * sizeof(u16));
  u16* wcl  = (u16*)alloc(128 * Kk * sizeof(u16));
  int* coff  = (int*)alloc((Nn + 1) * sizeof(int));
  int* cslot = (int*)alloc(ET * sizeof(int));

  k_prep<<<32, 256, 0, stream>>>(Wg, Wru, Wc, wgh, wgl, wruh, wrul, wch, wcl);
  k_csr<<<1, 256, 0, stream>>>(esrc, edst, coff, cslot);
  k_fused<<<Bb, 512, 0, stream>>>(stt, inp, wgh, wgl, att_s, att_d, coff, cslot,
                                  gbias, b1, wruh, wrul, bru, wch, wcl, bc, out);
}